// Round 1
// baseline (231.289 us; speedup 1.0000x reference)
//
#include <hip/hip_runtime.h>
#include <stdint.h>

#define NBINS 256
#define BATCH 16
#define HW (1024*1024)           // pixels per batch image
#define NPIX (BATCH * HW)        // 16,777,216 total pixels

// ---------------------------------------------------------------------------
// Kernel 1: per-batch histogram (all in-range pixels) + valid-pixel histogram.
// Packed LDS counter: low 16 bits = in-range count, high 16 bits = valid count.
// Per block: 16384 pixels -> max per-bin count 16384, fits both halves.
// ---------------------------------------------------------------------------
__global__ __launch_bounds__(256) void hist_kernel(const float* __restrict__ in,
                                                   unsigned* __restrict__ ghist,
                                                   unsigned* __restrict__ gvhist) {
    __shared__ unsigned sh[NBINS];
    const int tid = threadIdx.x;
    const int batch = blockIdx.y;
    for (int i = tid; i < NBINS; i += 256) sh[i] = 0;
    __syncthreads();

    // each block: 4096 float4 = 16384 floats of one batch image
    const float4* src = (const float4*)(in + (size_t)batch * HW) + (size_t)blockIdx.x * 4096;
    for (int i = tid; i < 4096; i += 256) {
        float4 x = src[i];
        float v[4] = {x.x, x.y, x.z, x.w};
#pragma unroll
        for (int k = 0; k < 4; ++k) {
            float mi = v[k] * 255.0f;                 // replicate reference arithmetic
            if (mi >= 0.0f && mi <= 255.0f) {         // jnp.histogram range=(0,255), edges inclusive
                int b = (int)(mi * (256.0f / 255.0f));
                if (b > 255) b = 255;                 // right edge -> last bin
                float r = rintf(mi);                  // round-half-even == jnp.round
                unsigned add = (mi == r) ? 0x10001u : 1u; // valid pixels: in-range & integral
                atomicAdd(&sh[b], add);
            }
        }
    }
    __syncthreads();
    for (int i = tid; i < NBINS; i += 256) {
        unsigned p = sh[i];
        if (p) {
            atomicAdd(&ghist[batch * NBINS + i], p & 0xFFFFu);
            atomicAdd(&gvhist[batch * NBINS + i], p >> 16);
        }
    }
}

// ---------------------------------------------------------------------------
// Kernel 2: per-batch flag.
// mask.max() > 0  <=>  exists bin j: vhist[j] > 0 and (total_hist - hist[j]) > 0
// (mask_output[j] = sum_k |j-k| * hist[k]; all terms are non-negative integers,
//  so the f32 matvec is > 0 iff any hist mass exists at k != j.)
// ---------------------------------------------------------------------------
__global__ __launch_bounds__(256) void flag_kernel(const unsigned* __restrict__ ghist,
                                                   const unsigned* __restrict__ gvhist,
                                                   unsigned* __restrict__ flags) {
    __shared__ unsigned stot[NBINS];
    __shared__ int any;
    const int b = blockIdx.x;
    const int j = threadIdx.x;
    unsigned h = ghist[b * NBINS + j];
    unsigned v = gvhist[b * NBINS + j];
    if (j == 0) any = 0;
    stot[j] = h;
    __syncthreads();
    for (int s = 128; s > 0; s >>= 1) {
        if (j < s) stot[j] += stot[j + s];
        __syncthreads();
    }
    unsigned total = stot[0];
    if (v > 0 && total > h) any = 1;   // benign race: all writers store 1
    __syncthreads();
    if (j == 0) flags[b] = (unsigned)any;
}

// ---------------------------------------------------------------------------
// Kernel 3: fused mask-apply + 2-way softmax, float4 vectorized.
// m = flag ? (x*255)/255 : 0 ; out0 = softmax(m, 1-m)[0]; out1 = [1].
// Output layout: [msks0 (16M floats) | msks1 (16M floats)].
// ---------------------------------------------------------------------------
__device__ __forceinline__ void softmax2(float x, unsigned flag, float& o0, float& o1) {
    float mi = x * 255.0f;
    float m = flag ? (mi / 255.0f) : 0.0f;
    float a = m;
    float b = 1.0f - m;
    float M = fmaxf(a, b);
    float e0 = expf(a - M);
    float e1 = expf(b - M);
    float s = e0 + e1;
    o0 = e0 / s;
    o1 = e1 / s;
}

__global__ __launch_bounds__(256) void out_kernel(const float* __restrict__ in,
                                                  const unsigned* __restrict__ flags,
                                                  float* __restrict__ out) {
    const size_t i4 = (size_t)blockIdx.x * 256 + threadIdx.x;  // float4 index, 4,194,304 total
    const int batch = (int)(i4 >> 18);                          // (i4*4) >> 20
    const unsigned f = flags[batch];
    float4 x = ((const float4*)in)[i4];
    float4 o0, o1;
    softmax2(x.x, f, o0.x, o1.x);
    softmax2(x.y, f, o0.y, o1.y);
    softmax2(x.z, f, o0.z, o1.z);
    softmax2(x.w, f, o0.w, o1.w);
    ((float4*)out)[i4] = o0;
    ((float4*)(out + (size_t)NPIX))[i4] = o1;
}

// ---------------------------------------------------------------------------
extern "C" void kernel_launch(void* const* d_in, const int* in_sizes, int n_in,
                              void* d_out, int out_size, void* d_ws, size_t ws_size,
                              hipStream_t stream) {
    const float* irr = (const float*)d_in[0];
    // d_in[1] (image_vis) is unused by the reference's outputs.
    float* out = (float*)d_out;

    unsigned* ghist  = (unsigned*)d_ws;
    unsigned* gvhist = ghist + BATCH * NBINS;
    unsigned* flags  = gvhist + BATCH * NBINS;

    // ws is poisoned 0xAA before every launch -> zero the counters we use.
    hipMemsetAsync(d_ws, 0, (size_t)(2 * BATCH * NBINS + BATCH) * sizeof(unsigned), stream);

    hist_kernel<<<dim3(64, BATCH), 256, 0, stream>>>(irr, ghist, gvhist);
    flag_kernel<<<BATCH, 256, 0, stream>>>(ghist, gvhist, flags);
    out_kernel<<<NPIX / 4 / 256, 256, 0, stream>>>(irr, flags, out);
}

// Round 2
// 230.486 us; speedup vs baseline: 1.0035x; 1.0035x over previous
//
#include <hip/hip_runtime.h>
#include <stdint.h>

#define NBINS 256
#define BATCH 16
#define HW (1024*1024)           // pixels per batch image
#define NPIX (BATCH * HW)        // 16,777,216 total pixels
#define SCAN_BLOCKS 64           // blocks per batch in scan kernel

// ---------------------------------------------------------------------------
// Kernel 1: streaming reduction per block ->
//   minb  = min occupied histogram bin (0x7FFF if none in-range)
//   maxb  = max occupied histogram bin (-1 if none)
//   valid = any pixel with integral mi in [0,255]
// Rationale: mask.max()>0  <=>  (any valid pixel) AND (>=2 distinct occupied
// bins). For a valid pixel mi=n (integer 0..255) its bin index equals n, so
// total>hist[n] iff another bin is occupied; with exactly one occupied bin
// every valid pixel's mask_output entry is 0.
// ---------------------------------------------------------------------------
__global__ __launch_bounds__(256) void scan_kernel(const float* __restrict__ in,
                                                   uint2* __restrict__ partials) {
    __shared__ int smin[256], smax[256];
    __shared__ unsigned sval[256];
    const int tid = threadIdx.x;
    const int batch = blockIdx.y;

    int minb = 0x7FFF, maxb = -1;
    unsigned valid = 0;

    // each block: 4096 float4 = 16384 floats of one batch image
    const float4* src = (const float4*)(in + (size_t)batch * HW) + (size_t)blockIdx.x * 4096;
    for (int i = tid; i < 4096; i += 256) {
        float4 x = src[i];
        float v[4] = {x.x, x.y, x.z, x.w};
#pragma unroll
        for (int k = 0; k < 4; ++k) {
            float mi = v[k] * 255.0f;                 // replicate reference arithmetic
            if (mi >= 0.0f && mi <= 255.0f) {         // histogram range (edges inclusive)
                int b = (int)(mi * (256.0f / 255.0f));
                if (b > 255) b = 255;                 // right edge -> last bin
                minb = min(minb, b);
                maxb = max(maxb, b);
                valid |= (mi == rintf(mi)) ? 1u : 0u; // round-half-even == jnp.round
            }
        }
    }
    smin[tid] = minb; smax[tid] = maxb; sval[tid] = valid;
    __syncthreads();
    for (int s = 128; s > 0; s >>= 1) {
        if (tid < s) {
            smin[tid] = min(smin[tid], smin[tid + s]);
            smax[tid] = max(smax[tid], smax[tid + s]);
            sval[tid] |= sval[tid + s];
        }
        __syncthreads();
    }
    if (tid == 0) {
        uint2 p;
        p.x = ((unsigned)(smin[0] & 0xFFFF) << 16) | (unsigned)(smax[0] & 0xFFFF);
        p.y = sval[0];
        partials[batch * SCAN_BLOCKS + blockIdx.x] = p;
    }
}

// ---------------------------------------------------------------------------
// Kernel 2: combine 64 per-block partials per batch -> flag.
// One wave (64 lanes) per batch; butterfly shuffle reduction.
// ---------------------------------------------------------------------------
__global__ __launch_bounds__(64) void flag_kernel(const uint2* __restrict__ partials,
                                                  unsigned* __restrict__ flags) {
    const int b = blockIdx.x;
    const int t = threadIdx.x;
    uint2 p = partials[b * SCAN_BLOCKS + t];
    int minb = (int)(short)(p.x >> 16);     // sign-extend: 0x7FFF stays, maxb -1 stays
    int maxb = (int)(short)(p.x & 0xFFFF);
    unsigned valid = p.y;
#pragma unroll
    for (int off = 32; off > 0; off >>= 1) {
        minb = min(minb, __shfl_xor(minb, off));
        maxb = max(maxb, __shfl_xor(maxb, off));
        valid |= (unsigned)__shfl_xor((int)valid, off);
    }
    if (t == 0) flags[b] = (valid && (minb != maxb)) ? 1u : 0u;
}

// ---------------------------------------------------------------------------
// Kernel 3: fused mask-apply + 2-way softmax, float4 vectorized.
// m = flag ? (x*255)/255 : 0 ; out = softmax(m, 1-m).
// Output layout: [msks0 (16M floats) | msks1 (16M floats)].
// ---------------------------------------------------------------------------
__device__ __forceinline__ void softmax2(float x, unsigned flag, float& o0, float& o1) {
    float mi = x * 255.0f;
    float m = flag ? (mi / 255.0f) : 0.0f;
    float a = m;
    float b = 1.0f - m;
    float M = fmaxf(a, b);
    float e0 = expf(a - M);
    float e1 = expf(b - M);
    float s = e0 + e1;
    o0 = e0 / s;
    o1 = e1 / s;
}

__global__ __launch_bounds__(256) void out_kernel(const float* __restrict__ in,
                                                  const unsigned* __restrict__ flags,
                                                  float* __restrict__ out) {
    const size_t i4 = (size_t)blockIdx.x * 256 + threadIdx.x;  // float4 index
    const int batch = (int)(i4 >> 18);                          // (i4*4) >> 20
    const unsigned f = flags[batch];
    float4 x = ((const float4*)in)[i4];
    float4 o0, o1;
    softmax2(x.x, f, o0.x, o1.x);
    softmax2(x.y, f, o0.y, o1.y);
    softmax2(x.z, f, o0.z, o1.z);
    softmax2(x.w, f, o0.w, o1.w);
    ((float4*)out)[i4] = o0;
    ((float4*)(out + (size_t)NPIX))[i4] = o1;
}

// ---------------------------------------------------------------------------
extern "C" void kernel_launch(void* const* d_in, const int* in_sizes, int n_in,
                              void* d_out, int out_size, void* d_ws, size_t ws_size,
                              hipStream_t stream) {
    const float* irr = (const float*)d_in[0];
    // d_in[1] (image_vis) is unused by the reference's outputs.
    float* out = (float*)d_out;

    uint2* partials = (uint2*)d_ws;                      // 16*64 uint2 = 8 KB
    unsigned* flags = (unsigned*)(partials + BATCH * SCAN_BLOCKS);
    // No memset needed: partials fully written by scan_kernel, flags by flag_kernel.

    scan_kernel<<<dim3(SCAN_BLOCKS, BATCH), 256, 0, stream>>>(irr, partials);
    flag_kernel<<<BATCH, 64, 0, stream>>>(partials, flags);
    out_kernel<<<NPIX / 4 / 256, 256, 0, stream>>>(irr, flags, out);
}